// Round 6
// baseline (452.102 us; speedup 1.0000x reference)
//
#include <hip/hip_runtime.h>

#define N_NODES 50000
#define N_EDGES 800000
#define N2 (2*N_NODES)
#define IN_C 8
#define OUT_C 16
#define EDGE_F 8
#define HEADS 4
#define HID 64
#define GDIM (HEADS*HID)   // 256
#define FINAL 128
#define NEG_SLOPE 0.2f
#define EB ((N_EDGES+255)/256)      // 3125
#define YB ((N_NODES*16+255)/256)   // 3125
#define NBLK2 ((N2+255)/256)        // 391

__device__ __forceinline__ int clampn(int v) {
    return v < 0 ? 0 : (v >= N_NODES ? N_NODES - 1 : v);
}
__device__ __forceinline__ unsigned short f32_to_bf16(float f) {
    unsigned u = __float_as_uint(f);
    unsigned r = (u + 0x7fffu + ((u >> 16) & 1u)) >> 16;   // RNE
    return (unsigned short)r;
}
__device__ __forceinline__ float bf16_to_f32(unsigned short h) {
    return __uint_as_float(((unsigned)h) << 16);
}
__device__ __forceinline__ float bf16lo(unsigned u) { return __uint_as_float(u << 16); }
__device__ __forceinline__ float bf16hi(unsigned u) { return __uint_as_float(u & 0xffff0000u); }

// ---------- K_hist_y: dual histogram (dst + src) fused with per-node Y/z precompute ----------
__global__ __launch_bounds__(256) void k_hist_y(
    const int* __restrict__ src, const int* __restrict__ dst,
    int* __restrict__ cnt, int* __restrict__ rnk_d, int* __restrict__ rnk_s,
    const float* __restrict__ x,
    const float* __restrict__ mlp_w, const float* __restrict__ mlp_b,
    uint4* __restrict__ Y4, float* __restrict__ z)
{
    if (blockIdx.x < EB) {
        int e = blockIdx.x * 256 + threadIdx.x;
        if (e >= N_EDGES) return;
        rnk_d[e] = atomicAdd(&cnt[clampn(dst[e])], 1);
        rnk_s[e] = atomicAdd(&cnt[N_NODES + clampn(src[e])], 1);
    } else {
        __shared__ float smw[EDGE_F * IN_C * OUT_C];  // 1024
        __shared__ float smb[IN_C * OUT_C];           // 128
        for (int i = threadIdx.x; i < EDGE_F * IN_C * OUT_C; i += 256) smw[i] = mlp_w[i];
        for (int i = threadIdx.x; i < IN_C * OUT_C; i += 256) smb[i] = mlp_b[i];
        __syncthreads();

        int t = (blockIdx.x - EB) * 256 + threadIdx.x;
        int n = t >> 4, o = t & 15;
        if (n >= N_NODES) return;

        float xv[IN_C];
#pragma unroll
        for (int i = 0; i < IN_C; i++) xv[i] = x[n * IN_C + i];

        float zf = 0.f;
#pragma unroll
        for (int i = 0; i < IN_C; i++) zf += xv[i] * smb[i * OUT_C + o];
        z[n * OUT_C + o] = zf;

        unsigned pk[4];
#pragma unroll
        for (int f2 = 0; f2 < EDGE_F; f2 += 2) {
            float y0 = 0.f, y1 = 0.f;
#pragma unroll
            for (int i = 0; i < IN_C; i++) {
                y0 += xv[i] * smw[f2 * (IN_C * OUT_C) + i * OUT_C + o];
                y1 += xv[i] * smw[(f2 + 1) * (IN_C * OUT_C) + i * OUT_C + o];
            }
            pk[f2 >> 1] = (unsigned)f32_to_bf16(y0) | ((unsigned)f32_to_bf16(y1) << 16);
        }
        Y4[(size_t)n * OUT_C + o] = make_uint4(pk[0], pk[1], pk[2], pk[3]);
    }
}

// ---------- scan pipeline over the 2N concatenated counters ----------
__global__ __launch_bounds__(256) void k_part(const int* __restrict__ cnt,
                                              int* __restrict__ part)
{
    int i = blockIdx.x * 256 + threadIdx.x;
    int v = (i < N2) ? cnt[i] : 0;
#pragma unroll
    for (int off = 32; off; off >>= 1) v += __shfl_down(v, off);
    __shared__ int ws[4];
    if ((threadIdx.x & 63) == 0) ws[threadIdx.x >> 6] = v;
    __syncthreads();
    if (threadIdx.x == 0) part[blockIdx.x] = ws[0] + ws[1] + ws[2] + ws[3];
}

__global__ __launch_bounds__(512) void k_scan1(const int* __restrict__ part,
                                               int* __restrict__ partscan)
{
    int t = threadIdx.x;
    int v = (t < NBLK2) ? part[t] : 0;
    int lane = t & 63, wid = t >> 6;
    int incl = v;
#pragma unroll
    for (int off = 1; off < 64; off <<= 1) {
        int u = __shfl_up(incl, off);
        if (lane >= off) incl += u;
    }
    __shared__ int wsum[8];
    if (lane == 63) wsum[wid] = incl;
    __syncthreads();
    int add = 0;
    for (int w = 0; w < wid; w++) add += wsum[w];
    partscan[t] = incl - v + add;   // exclusive
}

__global__ __launch_bounds__(256) void k_add2(const int* __restrict__ cnt,
                                              const int* __restrict__ partscan,
                                              int* __restrict__ offs_all)
{
    int i = blockIdx.x * 256 + threadIdx.x;
    int v = (i < N2) ? cnt[i] : 0;
    int lane = threadIdx.x & 63, wid = threadIdx.x >> 6;
    int incl = v;
#pragma unroll
    for (int off = 1; off < 64; off <<= 1) {
        int u = __shfl_up(incl, off);
        if (lane >= off) incl += u;
    }
    __shared__ int wsum[4];
    if (lane == 63) wsum[wid] = incl;
    __syncthreads();
    int add = partscan[blockIdx.x];
    for (int w = 0; w < wid; w++) add += wsum[w];
    if (i < N2) offs_all[i] = incl - v + add;
    if (i == 0) offs_all[N2] = 2 * N_EDGES;
}

// ---------- K_scatter2: build dst-CSR src list + src-CSC (edge id + csr position) ----------
__global__ __launch_bounds__(256) void k_scatter2(
    const int* __restrict__ src, const int* __restrict__ dst,
    const int* __restrict__ rnk_d, const int* __restrict__ rnk_s,
    const int* __restrict__ offs_all,
    int* __restrict__ src_csr, int* __restrict__ csc_ed, int* __restrict__ csc_pd)
{
    int e = blockIdx.x * 256 + threadIdx.x;
    if (e >= N_EDGES) return;
    int d = clampn(dst[e]), s = clampn(src[e]);
    int pd = offs_all[d] + rnk_d[e];
    int ps = offs_all[N_NODES + s] - N_EDGES + rnk_s[e];
    src_csr[pd] = s;
    csc_ed[ps] = e;
    csc_pd[ps] = pd;
}

// ---------- K_nn_src: src-major NNConv messages; Y[s] read ONCE, msg scattered to CSR slot ----------
__global__ __launch_bounds__(256) void k_nn_src(
    const int* __restrict__ offs_all, const int* __restrict__ csc_ed,
    const int* __restrict__ csc_pd, const float* __restrict__ ea,
    const uint4* __restrict__ Y4, const float* __restrict__ z,
    unsigned short* __restrict__ msgbuf)
{
    int wid = threadIdx.x >> 6, lane = threadIdx.x & 63;
    int s = blockIdx.x * 4 + wid;
    if (s >= N_NODES) return;
    int o = lane & 15, el = lane >> 4;
    int beg = offs_all[N_NODES + s] - N_EDGES;
    int end = offs_all[N_NODES + s + 1] - N_EDGES;

    uint4 yv = Y4[(size_t)s * OUT_C + o];
    float zf = z[s * OUT_C + o];
    float y0 = bf16lo(yv.x), y1 = bf16hi(yv.x), y2 = bf16lo(yv.y), y3 = bf16hi(yv.y);
    float y4 = bf16lo(yv.z), y5 = bf16hi(yv.z), y6 = bf16lo(yv.w), y7 = bf16hi(yv.w);

    for (int j = beg + el; j < end; j += 4) {
        int e = csc_ed[j];
        int p = csc_pd[j];
        float4 a0 = *(const float4*)&ea[(size_t)e * EDGE_F];
        float4 a1 = *(const float4*)&ea[(size_t)e * EDGE_F + 4];
        float m = zf + a0.x * y0 + a0.y * y1 + a0.z * y2 + a0.w * y3
                     + a1.x * y4 + a1.y * y5 + a1.z * y6 + a1.w * y7;
        float mo = __shfl_xor(m, 1);   // partner in same 16-lane group, same j
        if ((o & 1) == 0) {
            unsigned pk = (unsigned)f32_to_bf16(m) | ((unsigned)f32_to_bf16(mo) << 16);
            *(unsigned*)&msgbuf[(size_t)p * OUT_C + o] = pk;
        }
    }
}

// ---------- K2d: per-dst-node: sequential msg agg + node transform + attention logits ----------
__global__ __launch_bounds__(256) void k2d_node(
    const float* __restrict__ x, const unsigned short* __restrict__ msgbuf,
    const int* __restrict__ offs_all,
    const float* __restrict__ ecc_root, const float* __restrict__ ecc_bias,
    const float* __restrict__ gat_lin,
    const float* __restrict__ att_src_w, const float* __restrict__ att_dst_w,
    unsigned short* __restrict__ g_bf, float* __restrict__ asrc, float* __restrict__ adst)
{
    int wid = threadIdx.x >> 6, lane = threadIdx.x & 63;
    int n = blockIdx.x * 4 + wid;
    if (n >= N_NODES) return;

    int o = lane & 15, q = lane >> 4;
    int beg = offs_all[n], end = offs_all[n + 1];

    float aggv = 0.f;
    for (int j = beg + q; j < end; j += 4)
        aggv += bf16_to_f32(msgbuf[(size_t)j * OUT_C + o]);
    aggv += __shfl_down(aggv, 32);
    aggv += __shfl_down(aggv, 16);

    float hv = 0.f;
    if (lane < 16) {
        float v = ecc_bias[o] + aggv;
#pragma unroll
        for (int i = 0; i < IN_C; i++) v += x[n * IN_C + i] * ecc_root[i * OUT_C + o];
        hv = fmaxf(v, 0.f);
    }

    float gv[4] = {0.f, 0.f, 0.f, 0.f};
#pragma unroll
    for (int k = 0; k < OUT_C; k++) {
        float hk = __shfl(hv, k);
#pragma unroll
        for (int j = 0; j < 4; j++)
            gv[j] += hk * gat_lin[k * GDIM + j * 64 + lane];
    }
#pragma unroll
    for (int j = 0; j < 4; j++)
        g_bf[(size_t)n * GDIM + j * 64 + lane] = f32_to_bf16(gv[j]);

    float vs[4], vd[4];
#pragma unroll
    for (int j = 0; j < 4; j++) {
        vs[j] = gv[j] * att_src_w[j * 64 + lane];
        vd[j] = gv[j] * att_dst_w[j * 64 + lane];
    }
#pragma unroll
    for (int off = 32; off; off >>= 1) {
#pragma unroll
        for (int j = 0; j < 4; j++) {
            vs[j] += __shfl_down(vs[j], off);
            vd[j] += __shfl_down(vd[j], off);
        }
    }
    if (lane == 0) {
#pragma unroll
        for (int j = 0; j < 4; j++) {
            asrc[n * HEADS + j] = vs[j];
            adst[n * HEADS + j] = vd[j];
        }
    }
}

// ---------- K_gat: single-pass fused softmax + aggregate ----------
__global__ __launch_bounds__(256) void k_gat(
    const int* __restrict__ offs_all, const int* __restrict__ src_csr,
    const float* __restrict__ asrc, const float* __restrict__ adst,
    const unsigned short* __restrict__ g_bf, unsigned short* __restrict__ outg)
{
    int n = blockIdx.x;
    int t = threadIdx.x;
    int beg = offs_all[n], deg = offs_all[n + 1] - beg;

    __shared__ float s_adst[HEADS];
    __shared__ float s_al[64 * HEADS];
    __shared__ int   s_sid[64];
    __shared__ float s_wsum[4][HEADS];
    __shared__ float s_den[HEADS];
    __shared__ float s_acc[8][GDIM];

    int j = t >> 2, h = t & 3;
    int lane32 = t & 31, grp = t >> 5;
    int myhead = lane32 >> 3;

    if (t < HEADS) s_adst[t] = adst[n * HEADS + t];
    __syncthreads();

    float acc[8];
#pragma unroll
    for (int k = 0; k < 8; k++) acc[k] = 0.f;
    float denp = 0.f;

    for (int c0 = 0; c0 < deg; c0 += 64) {
        int nc = min(64, deg - c0);
        if (j < nc) {
            int s = src_csr[beg + c0 + j];
            if (h == 0) s_sid[j] = s;
            float v = asrc[s * HEADS + h] + s_adst[h];
            v = v > 0.f ? v : NEG_SLOPE * v;
            float p = __expf(v);
            s_al[j * HEADS + h] = p;
            denp += p;
        }
        __syncthreads();
        // 2 edges in flight per group for load-level parallelism
        for (int k8 = 0; k8 < nc; k8 += 16) {
            int e0 = k8 + grp, e1 = k8 + 8 + grp;
            if (e0 < nc) {
                int s0 = s_sid[e0];
                float a0 = s_al[e0 * HEADS + myhead];
                uint4 g0 = *(const uint4*)&g_bf[(size_t)s0 * GDIM + lane32 * 8];
                if (e1 < nc) {
                    int s1 = s_sid[e1];
                    float a1 = s_al[e1 * HEADS + myhead];
                    uint4 g1 = *(const uint4*)&g_bf[(size_t)s1 * GDIM + lane32 * 8];
                    acc[0] += a0 * bf16lo(g0.x) + a1 * bf16lo(g1.x);
                    acc[1] += a0 * bf16hi(g0.x) + a1 * bf16hi(g1.x);
                    acc[2] += a0 * bf16lo(g0.y) + a1 * bf16lo(g1.y);
                    acc[3] += a0 * bf16hi(g0.y) + a1 * bf16hi(g1.y);
                    acc[4] += a0 * bf16lo(g0.z) + a1 * bf16lo(g1.z);
                    acc[5] += a0 * bf16hi(g0.z) + a1 * bf16hi(g1.z);
                    acc[6] += a0 * bf16lo(g0.w) + a1 * bf16lo(g1.w);
                    acc[7] += a0 * bf16hi(g0.w) + a1 * bf16hi(g1.w);
                } else {
                    acc[0] += a0 * bf16lo(g0.x);
                    acc[1] += a0 * bf16hi(g0.x);
                    acc[2] += a0 * bf16lo(g0.y);
                    acc[3] += a0 * bf16hi(g0.y);
                    acc[4] += a0 * bf16lo(g0.z);
                    acc[5] += a0 * bf16hi(g0.z);
                    acc[6] += a0 * bf16lo(g0.w);
                    acc[7] += a0 * bf16hi(g0.w);
                }
            }
        }
        __syncthreads();
    }

#pragma unroll
    for (int mask = 4; mask < 64; mask <<= 1) denp += __shfl_xor(denp, mask);
    if ((t & 63) < 4) s_wsum[t >> 6][t & 3] = denp;
    // partials -> LDS as float4 (fewer, wider stores)
    *(float4*)&s_acc[grp][lane32 * 8]     = make_float4(acc[0], acc[1], acc[2], acc[3]);
    *(float4*)&s_acc[grp][lane32 * 8 + 4] = make_float4(acc[4], acc[5], acc[6], acc[7]);
    __syncthreads();
    if (t < HEADS)
        s_den[t] = s_wsum[0][t] + s_wsum[1][t] + s_wsum[2][t] + s_wsum[3][t];
    __syncthreads();

    float v = 0.f;
#pragma unroll
    for (int gIdx = 0; gIdx < 8; gIdx++) v += s_acc[gIdx][t];
    int head = t >> 6;
    outg[(size_t)n * GDIM + t] = f32_to_bf16(v / (s_den[head] + 1e-16f));
}

// ---------- K6: y = relu(outg + gat_bias) @ fc_w + fc_b ----------
#define BM 64
#define BK6 16
__global__ __launch_bounds__(256) void k6_final(
    const unsigned short* __restrict__ outg, const float* __restrict__ gat_bias,
    const float* __restrict__ fc_w, const float* __restrict__ fc_b,
    float* __restrict__ y)
{
    __shared__ float sA[BK6][BM + 4];
    __shared__ float sW[BK6][FINAL];
    int tid = threadIdx.x;
    int r0 = blockIdx.x * BM;
    int tcol = (tid & 31) * 4;
    int trow = (tid >> 5) * 8;

    float acc[8][4];
#pragma unroll
    for (int r = 0; r < 8; r++)
#pragma unroll
        for (int c = 0; c < 4; c++) acc[r][c] = 0.f;

    int ar = tid >> 2;
    int ak = (tid & 3) * 4;

    for (int k0 = 0; k0 < GDIM; k0 += BK6) {
        int row = r0 + ar;
        float4 av = make_float4(0.f, 0.f, 0.f, 0.f);
        if (row < N_NODES) {
            uint2 raw = *(const uint2*)&outg[(size_t)row * GDIM + k0 + ak];
            av = make_float4(bf16lo(raw.x), bf16hi(raw.x), bf16lo(raw.y), bf16hi(raw.y));
        }
        float4 bv = *(const float4*)&gat_bias[k0 + ak];
        av.x = fmaxf(av.x + bv.x, 0.f);
        av.y = fmaxf(av.y + bv.y, 0.f);
        av.z = fmaxf(av.z + bv.z, 0.f);
        av.w = fmaxf(av.w + bv.w, 0.f);
        sA[ak + 0][ar] = av.x;
        sA[ak + 1][ar] = av.y;
        sA[ak + 2][ar] = av.z;
        sA[ak + 3][ar] = av.w;
#pragma unroll
        for (int p = 0; p < 2; p++) {
            int kk = (tid >> 5) + p * 8;
            int c = (tid & 31) * 4;
            *(float4*)&sW[kk][c] = *(const float4*)&fc_w[(size_t)(k0 + kk) * FINAL + c];
        }
        __syncthreads();
#pragma unroll
        for (int kk = 0; kk < BK6; kk++) {
            float4 w = *(const float4*)&sW[kk][tcol];
            float4 a0 = *(const float4*)&sA[kk][trow];
            float4 a1 = *(const float4*)&sA[kk][trow + 4];
            float a[8] = {a0.x, a0.y, a0.z, a0.w, a1.x, a1.y, a1.z, a1.w};
#pragma unroll
            for (int r = 0; r < 8; r++) {
                acc[r][0] += a[r] * w.x;
                acc[r][1] += a[r] * w.y;
                acc[r][2] += a[r] * w.z;
                acc[r][3] += a[r] * w.w;
            }
        }
        __syncthreads();
    }

    float4 fb = *(const float4*)&fc_b[tcol];
#pragma unroll
    for (int r = 0; r < 8; r++) {
        int row = r0 + trow + r;
        if (row < N_NODES) {
            *(float4*)&y[(size_t)row * FINAL + tcol] =
                make_float4(acc[r][0] + fb.x, acc[r][1] + fb.y,
                            acc[r][2] + fb.z, acc[r][3] + fb.w);
        }
    }
}

extern "C" void kernel_launch(void* const* d_in, const int* in_sizes, int n_in,
                              void* d_out, int out_size, void* d_ws, size_t ws_size,
                              hipStream_t stream)
{
    const float* x        = (const float*)d_in[0];
    const int*   ei       = (const int*)d_in[1];
    const float* ea       = (const float*)d_in[2];
    const float* ecc_root = (const float*)d_in[3];
    const float* ecc_bias = (const float*)d_in[4];
    const float* mlp_w    = (const float*)d_in[5];
    const float* mlp_b    = (const float*)d_in[6];
    const float* gat_lin  = (const float*)d_in[7];
    const float* att_src  = (const float*)d_in[8];
    const float* att_dst  = (const float*)d_in[9];
    const float* gat_bias = (const float*)d_in[10];
    const float* fc_w     = (const float*)d_in[11];
    const float* fc_b     = (const float*)d_in[12];
    float* y = (float*)d_out;

    const int* src = ei;
    const int* dst = ei + N_EDGES;

    // workspace layout
    uint4* Y4 = (uint4*)d_ws;                                            // N*16 uint4 (12.8 MB)
    float* z  = (float*)(Y4 + (size_t)N_NODES * OUT_C);                  // N*16 f32 (3.2 MB)
    unsigned short* msgbuf = (unsigned short*)(z + (size_t)N_NODES * OUT_C); // E*16 bf16 (25.6 MB)
    unsigned short* g_bf   = msgbuf + (size_t)N_EDGES * OUT_C;           // N*256 bf16 (25.6 MB)
    float* asrc = (float*)(g_bf + (size_t)N_NODES * GDIM);               // N*4
    float* adst = asrc + (size_t)N_NODES * HEADS;                        // N*4
    int*   cnt      = (int*)(adst + (size_t)N_NODES * HEADS);            // 2N
    int*   offs_all = cnt + N2;                                          // 2N+1
    int*   part     = offs_all + N2 + 1;                                 // 512
    int*   partscan = part + 512;                                        // 512
    int*   rnk_d    = partscan + 512;                                    // E
    int*   rnk_s    = rnk_d + N_EDGES;                                   // E
    int*   src_csr  = rnk_s + N_EDGES;                                   // E
    int*   csc_ed   = src_csr + N_EDGES;                                 // E
    int*   csc_pd   = csc_ed + N_EDGES;                                  // E
    unsigned short* outg = msgbuf;  // alias: msgbuf dead after k2d

    hipMemsetAsync(cnt, 0, sizeof(int) * N2, stream);

    k_hist_y  <<<EB + YB, 256, 0, stream>>>(src, dst, cnt, rnk_d, rnk_s,
                                            x, mlp_w, mlp_b, Y4, z);
    k_part    <<<NBLK2, 256, 0, stream>>>(cnt, part);
    k_scan1   <<<1, 512, 0, stream>>>(part, partscan);
    k_add2    <<<NBLK2, 256, 0, stream>>>(cnt, partscan, offs_all);
    k_scatter2<<<EB, 256, 0, stream>>>(src, dst, rnk_d, rnk_s, offs_all,
                                       src_csr, csc_ed, csc_pd);

    k_nn_src  <<<(N_NODES + 3) / 4, 256, 0, stream>>>(offs_all, csc_ed, csc_pd,
                                                      ea, Y4, z, msgbuf);
    k2d_node  <<<(N_NODES + 3) / 4, 256, 0, stream>>>(x, msgbuf, offs_all,
                                                      ecc_root, ecc_bias, gat_lin,
                                                      att_src, att_dst, g_bf, asrc, adst);
    k_gat     <<<N_NODES, 256, 0, stream>>>(offs_all, src_csr, asrc, adst, g_bf, outg);
    k6_final  <<<(N_NODES + BM - 1) / BM, 256, 0, stream>>>(outg, gat_bias, fc_w, fc_b, y);
}

// Round 7
// 375.858 us; speedup vs baseline: 1.2029x; 1.2029x over previous
//
#include <hip/hip_runtime.h>

#define N_NODES 50000
#define N_EDGES 800000
#define IN_C 8
#define OUT_C 16
#define EDGE_F 8
#define HEADS 4
#define HID 64
#define GDIM (HEADS*HID)   // 256
#define FINAL 128
#define NEG_SLOPE 0.2f
#define EB ((N_EDGES+255)/256)      // 3125
#define YB ((N_NODES*16+255)/256)   // 3125
#define NBLK 196                    // ceil(N_NODES/256)

__device__ __forceinline__ int clampn(int v) {
    return v < 0 ? 0 : (v >= N_NODES ? N_NODES - 1 : v);
}
__device__ __forceinline__ unsigned short f32_to_bf16(float f) {
    unsigned u = __float_as_uint(f);
    unsigned r = (u + 0x7fffu + ((u >> 16) & 1u)) >> 16;   // RNE
    return (unsigned short)r;
}
__device__ __forceinline__ float bf16lo(unsigned u) { return __uint_as_float(u << 16); }
__device__ __forceinline__ float bf16hi(unsigned u) { return __uint_as_float(u & 0xffff0000u); }

// ---------- CSR build ----------
__global__ __launch_bounds__(256) void k_hist(const int* __restrict__ dst,
                                              int* __restrict__ cnt,
                                              int* __restrict__ rnk)
{
    int e = blockIdx.x * 256 + threadIdx.x;
    if (e >= N_EDGES) return;
    rnk[e] = atomicAdd(&cnt[clampn(dst[e])], 1);
}

__global__ __launch_bounds__(256) void k_part(const int* __restrict__ cnt,
                                              int* __restrict__ part)
{
    int i = blockIdx.x * 256 + threadIdx.x;
    int v = (i < N_NODES) ? cnt[i] : 0;
#pragma unroll
    for (int off = 32; off; off >>= 1) v += __shfl_down(v, off);
    __shared__ int ws[4];
    if ((threadIdx.x & 63) == 0) ws[threadIdx.x >> 6] = v;
    __syncthreads();
    if (threadIdx.x == 0) part[blockIdx.x] = ws[0] + ws[1] + ws[2] + ws[3];
}

__global__ __launch_bounds__(256) void k_scan1(const int* __restrict__ part,
                                               int* __restrict__ partscan)
{
    int t = threadIdx.x;
    int v = (t < NBLK) ? part[t] : 0;
    int lane = t & 63, wid = t >> 6;
    int incl = v;
#pragma unroll
    for (int off = 1; off < 64; off <<= 1) {
        int u = __shfl_up(incl, off);
        if (lane >= off) incl += u;
    }
    __shared__ int wsum[4];
    if (lane == 63) wsum[wid] = incl;
    __syncthreads();
    int add = 0;
    for (int w = 0; w < wid; w++) add += wsum[w];
    partscan[t] = incl - v + add;   // exclusive
}

__global__ __launch_bounds__(256) void k_add(const int* __restrict__ cnt,
                                             const int* __restrict__ partscan,
                                             int* __restrict__ offs)
{
    int i = blockIdx.x * 256 + threadIdx.x;
    int v = (i < N_NODES) ? cnt[i] : 0;
    int lane = threadIdx.x & 63, wid = threadIdx.x >> 6;
    int incl = v;
#pragma unroll
    for (int off = 1; off < 64; off <<= 1) {
        int u = __shfl_up(incl, off);
        if (lane >= off) incl += u;
    }
    __shared__ int wsum[4];
    if (lane == 63) wsum[wid] = incl;
    __syncthreads();
    int add = partscan[blockIdx.x];
    for (int w = 0; w < wid; w++) add += wsum[w];
    if (i < N_NODES) offs[i] = incl - v + add;
    if (i == 0) offs[N_NODES] = N_EDGES;
}

// ---------- K_scatter: (src, edge-id) pairs into dst-CSR order ----------
__global__ __launch_bounds__(256) void k_scatter(
    const int* __restrict__ src, const int* __restrict__ dst,
    const int* __restrict__ rnk, const int* __restrict__ offs,
    int2* __restrict__ se_csr)
{
    int e = blockIdx.x * 256 + threadIdx.x;
    if (e >= N_EDGES) return;
    int p = offs[clampn(dst[e])] + rnk[e];
    se_csr[p] = make_int2(clampn(src[e]), e);
}

// ---------- K0y: Y[n][o][f] = sum_i x[n,i]*W[f,i,o]  (bf16, 8 f per uint4) ----------
__global__ __launch_bounds__(256) void k0_y(
    const float* __restrict__ x, const float* __restrict__ mlp_w,
    uint4* __restrict__ Y4)
{
    __shared__ float smw[EDGE_F * IN_C * OUT_C];  // 1024
    for (int i = threadIdx.x; i < EDGE_F * IN_C * OUT_C; i += 256) smw[i] = mlp_w[i];
    __syncthreads();

    int t = blockIdx.x * 256 + threadIdx.x;
    int n = t >> 4, o = t & 15;
    if (n >= N_NODES) return;

    float xv[IN_C];
#pragma unroll
    for (int i = 0; i < IN_C; i++) xv[i] = x[n * IN_C + i];

    unsigned pk[4];
#pragma unroll
    for (int f2 = 0; f2 < EDGE_F; f2 += 2) {
        float y0 = 0.f, y1 = 0.f;
#pragma unroll
        for (int i = 0; i < IN_C; i++) {
            y0 += xv[i] * smw[f2 * (IN_C * OUT_C) + i * OUT_C + o];
            y1 += xv[i] * smw[(f2 + 1) * (IN_C * OUT_C) + i * OUT_C + o];
        }
        pk[f2 >> 1] = (unsigned)f32_to_bf16(y0) | ((unsigned)f32_to_bf16(y1) << 16);
    }
    Y4[(size_t)n * OUT_C + o] = make_uint4(pk[0], pk[1], pk[2], pk[3]);
}

// ---------- K2c: fused NNConv aggregate + node transform + attention logits ----------
// One wave per node; 4 groups of 16 lanes; per edge: agg[o] += att.Y[s,:,o],
// xs[f] += x[s,f]  (bias term folded: sum_e z[s_e] = xs . mlp_b)
__global__ __launch_bounds__(256) void k2c_node(
    const float* __restrict__ x, const uint4* __restrict__ Y4,
    const int2* __restrict__ se_csr, const int* __restrict__ offs,
    const float* __restrict__ ea, const float* __restrict__ mlp_b,
    const float* __restrict__ ecc_root, const float* __restrict__ ecc_bias,
    const float* __restrict__ gat_lin,
    const float* __restrict__ att_src_w, const float* __restrict__ att_dst_w,
    unsigned short* __restrict__ g_bf, float* __restrict__ asrc, float* __restrict__ adst)
{
    int wid = threadIdx.x >> 6, lane = threadIdx.x & 63;
    int n = blockIdx.x * 4 + wid;
    if (n >= N_NODES) return;

    int o = lane & 15, el = lane >> 4;
    int beg = offs[n], end = offs[n + 1];

    float aggv = 0.f, xs = 0.f;
    for (int j = beg + el; j < end; j += 4) {
        int2 se = se_csr[j];
        int s = se.x, e = se.y;
        float4 a0 = *(const float4*)&ea[(size_t)e * EDGE_F];      // broadcast
        float4 a1 = *(const float4*)&ea[(size_t)e * EDGE_F + 4];
        uint4 yv = Y4[(size_t)s * OUT_C + o];                     // 256 B/edge
        aggv += a0.x * bf16lo(yv.x) + a0.y * bf16hi(yv.x)
              + a0.z * bf16lo(yv.y) + a0.w * bf16hi(yv.y)
              + a1.x * bf16lo(yv.z) + a1.y * bf16hi(yv.z)
              + a1.z * bf16lo(yv.w) + a1.w * bf16hi(yv.w);
        xs += x[s * IN_C + (o & 7)];                              // 32 B broadcast
    }
    aggv += __shfl_down(aggv, 32);
    aggv += __shfl_down(aggv, 16);    // lanes 0..15: agg per o
    xs += __shfl_down(xs, 32);
    xs += __shfl_down(xs, 16);        // lanes 0..7: xs per input feature

    float hv = 0.f;
    if (lane < 16) {
        float v = ecc_bias[o] + aggv;
#pragma unroll
        for (int i = 0; i < IN_C; i++) {
            float xsi = __shfl(xs, i);    // lanes 0..7 hold xs_i
            v += xsi * mlp_b[i * OUT_C + o];
            v += x[n * IN_C + i] * ecc_root[i * OUT_C + o];
        }
        hv = fmaxf(v, 0.f);
    }

    float gv[4] = {0.f, 0.f, 0.f, 0.f};
#pragma unroll
    for (int k = 0; k < OUT_C; k++) {
        float hk = __shfl(hv, k);
#pragma unroll
        for (int j = 0; j < 4; j++)
            gv[j] += hk * gat_lin[k * GDIM + j * 64 + lane];
    }
#pragma unroll
    for (int j = 0; j < 4; j++)
        g_bf[(size_t)n * GDIM + j * 64 + lane] = f32_to_bf16(gv[j]);

    float vs[4], vd[4];
#pragma unroll
    for (int j = 0; j < 4; j++) {
        vs[j] = gv[j] * att_src_w[j * 64 + lane];
        vd[j] = gv[j] * att_dst_w[j * 64 + lane];
    }
#pragma unroll
    for (int off = 32; off; off >>= 1) {
#pragma unroll
        for (int j = 0; j < 4; j++) {
            vs[j] += __shfl_down(vs[j], off);
            vd[j] += __shfl_down(vd[j], off);
        }
    }
    if (lane == 0) {
#pragma unroll
        for (int j = 0; j < 4; j++) {
            asrc[n * HEADS + j] = vs[j];
            adst[n * HEADS + j] = vd[j];
        }
    }
}

// ---------- K_gat v3: single-loop fused softmax+aggregate, inline alpha ----------
// 8 groups x 32 lanes; group g owns edges j = g, g+8, ...; lane owns 8 dims
// (one head per 8-lane octet), computes exp inline (redundant x8, cheap),
// accumulates p*g[s] and its own denom partial. ONE barrier per block.
__global__ __launch_bounds__(256) void k_gat(
    const int* __restrict__ offs, const int2* __restrict__ se_csr,
    const float* __restrict__ asrc, const float* __restrict__ adst,
    const unsigned short* __restrict__ g_bf, unsigned short* __restrict__ outg)
{
    int n = blockIdx.x, t = threadIdx.x;
    int lane32 = t & 31, grp = t >> 5;
    int hh = lane32 >> 3;
    int beg = offs[n], deg = offs[n + 1] - beg;

    float adsth = adst[n * HEADS + hh];

    float acc[8];
#pragma unroll
    for (int k = 0; k < 8; k++) acc[k] = 0.f;
    float denp = 0.f;

    for (int j = grp; j < deg; j += 8) {
        int s = se_csr[beg + j].x;
        float v = asrc[s * HEADS + hh] + adsth;
        v = v > 0.f ? v : NEG_SLOPE * v;
        float p = __expf(v);
        denp += p;
        uint4 gv = *(const uint4*)&g_bf[(size_t)s * GDIM + lane32 * 8];
        acc[0] += p * bf16lo(gv.x);
        acc[1] += p * bf16hi(gv.x);
        acc[2] += p * bf16lo(gv.y);
        acc[3] += p * bf16hi(gv.y);
        acc[4] += p * bf16lo(gv.z);
        acc[5] += p * bf16hi(gv.z);
        acc[6] += p * bf16lo(gv.w);
        acc[7] += p * bf16hi(gv.w);
    }

    __shared__ float s_acc[8][GDIM];    // 8 KB
    __shared__ float s_den[8][HEADS];
    *(float4*)&s_acc[grp][lane32 * 8]     = make_float4(acc[0], acc[1], acc[2], acc[3]);
    *(float4*)&s_acc[grp][lane32 * 8 + 4] = make_float4(acc[4], acc[5], acc[6], acc[7]);
    if ((lane32 & 7) == 0) s_den[grp][hh] = denp;
    __syncthreads();

    int head = t >> 6;
    float den = 0.f, v = 0.f;
#pragma unroll
    for (int g2 = 0; g2 < 8; g2++) {
        den += s_den[g2][head];
        v += s_acc[g2][t];
    }
    outg[(size_t)n * GDIM + t] = f32_to_bf16(v / (den + 1e-16f));
}

// ---------- K6: y = relu(outg + gat_bias) @ fc_w + fc_b ----------
#define BM 64
#define BK6 16
__global__ __launch_bounds__(256) void k6_final(
    const unsigned short* __restrict__ outg, const float* __restrict__ gat_bias,
    const float* __restrict__ fc_w, const float* __restrict__ fc_b,
    float* __restrict__ y)
{
    __shared__ float sA[BK6][BM + 4];
    __shared__ float sW[BK6][FINAL];
    int tid = threadIdx.x;
    int r0 = blockIdx.x * BM;
    int tcol = (tid & 31) * 4;
    int trow = (tid >> 5) * 8;

    float acc[8][4];
#pragma unroll
    for (int r = 0; r < 8; r++)
#pragma unroll
        for (int c = 0; c < 4; c++) acc[r][c] = 0.f;

    int ar = tid >> 2;
    int ak = (tid & 3) * 4;

    for (int k0 = 0; k0 < GDIM; k0 += BK6) {
        int row = r0 + ar;
        float4 av = make_float4(0.f, 0.f, 0.f, 0.f);
        if (row < N_NODES) {
            uint2 raw = *(const uint2*)&outg[(size_t)row * GDIM + k0 + ak];
            av = make_float4(bf16lo(raw.x), bf16hi(raw.x), bf16lo(raw.y), bf16hi(raw.y));
        }
        float4 bv = *(const float4*)&gat_bias[k0 + ak];
        av.x = fmaxf(av.x + bv.x, 0.f);
        av.y = fmaxf(av.y + bv.y, 0.f);
        av.z = fmaxf(av.z + bv.z, 0.f);
        av.w = fmaxf(av.w + bv.w, 0.f);
        sA[ak + 0][ar] = av.x;
        sA[ak + 1][ar] = av.y;
        sA[ak + 2][ar] = av.z;
        sA[ak + 3][ar] = av.w;
#pragma unroll
        for (int p = 0; p < 2; p++) {
            int kk = (tid >> 5) + p * 8;
            int c = (tid & 31) * 4;
            *(float4*)&sW[kk][c] = *(const float4*)&fc_w[(size_t)(k0 + kk) * FINAL + c];
        }
        __syncthreads();
#pragma unroll
        for (int kk = 0; kk < BK6; kk++) {
            float4 w = *(const float4*)&sW[kk][tcol];
            float4 a0 = *(const float4*)&sA[kk][trow];
            float4 a1 = *(const float4*)&sA[kk][trow + 4];
            float a[8] = {a0.x, a0.y, a0.z, a0.w, a1.x, a1.y, a1.z, a1.w};
#pragma unroll
            for (int r = 0; r < 8; r++) {
                acc[r][0] += a[r] * w.x;
                acc[r][1] += a[r] * w.y;
                acc[r][2] += a[r] * w.z;
                acc[r][3] += a[r] * w.w;
            }
        }
        __syncthreads();
    }

    float4 fb = *(const float4*)&fc_b[tcol];
#pragma unroll
    for (int r = 0; r < 8; r++) {
        int row = r0 + trow + r;
        if (row < N_NODES) {
            *(float4*)&y[(size_t)row * FINAL + tcol] =
                make_float4(acc[r][0] + fb.x, acc[r][1] + fb.y,
                            acc[r][2] + fb.z, acc[r][3] + fb.w);
        }
    }
}

extern "C" void kernel_launch(void* const* d_in, const int* in_sizes, int n_in,
                              void* d_out, int out_size, void* d_ws, size_t ws_size,
                              hipStream_t stream)
{
    const float* x        = (const float*)d_in[0];
    const int*   ei       = (const int*)d_in[1];
    const float* ea       = (const float*)d_in[2];
    const float* ecc_root = (const float*)d_in[3];
    const float* ecc_bias = (const float*)d_in[4];
    const float* mlp_w    = (const float*)d_in[5];
    const float* mlp_b    = (const float*)d_in[6];
    const float* gat_lin  = (const float*)d_in[7];
    const float* att_src  = (const float*)d_in[8];
    const float* att_dst  = (const float*)d_in[9];
    const float* gat_bias = (const float*)d_in[10];
    const float* fc_w     = (const float*)d_in[11];
    const float* fc_b     = (const float*)d_in[12];
    float* y = (float*)d_out;

    const int* src = ei;
    const int* dst = ei + N_EDGES;

    // workspace layout
    uint4* Y4 = (uint4*)d_ws;                                            // N*16 uint4 (12.8 MB)
    unsigned short* g_bf = (unsigned short*)(Y4 + (size_t)N_NODES * OUT_C); // N*256 bf16 (25.6 MB)
    unsigned short* outg = g_bf + (size_t)N_NODES * GDIM;                // N*256 bf16 (25.6 MB)
    float* asrc = (float*)(outg + (size_t)N_NODES * GDIM);               // N*4
    float* adst = asrc + (size_t)N_NODES * HEADS;                        // N*4
    int*   cnt      = (int*)(adst + (size_t)N_NODES * HEADS);            // N
    int*   offs     = cnt + N_NODES;                                     // N+1
    int*   part     = offs + N_NODES + 1;                                // 256
    int*   partscan = part + 256;                                        // 256
    int*   rnk      = partscan + 256;                                    // E
    int2*  se_csr   = (int2*)(rnk + N_EDGES);                            // E int2 (6.4 MB)

    hipMemsetAsync(cnt, 0, sizeof(int) * N_NODES, stream);

    k_hist   <<<EB, 256, 0, stream>>>(dst, cnt, rnk);
    k0_y     <<<YB, 256, 0, stream>>>(x, mlp_w, Y4);
    k_part   <<<NBLK, 256, 0, stream>>>(cnt, part);
    k_scan1  <<<1, 256, 0, stream>>>(part, partscan);
    k_add    <<<NBLK, 256, 0, stream>>>(cnt, partscan, offs);
    k_scatter<<<EB, 256, 0, stream>>>(src, dst, rnk, offs, se_csr);

    k2c_node <<<(N_NODES + 3) / 4, 256, 0, stream>>>(x, Y4, se_csr, offs, ea, mlp_b,
                                                     ecc_root, ecc_bias, gat_lin,
                                                     att_src, att_dst, g_bf, asrc, adst);
    k_gat    <<<N_NODES, 256, 0, stream>>>(offs, se_csr, asrc, adst, g_bf, outg);
    k6_final <<<(N_NODES + BM - 1) / BM, 256, 0, stream>>>(outg, gat_bias, fc_w, fc_b, y);
}

// Round 8
// 374.300 us; speedup vs baseline: 1.2079x; 1.0042x over previous
//
#include <hip/hip_runtime.h>

#define N_NODES 50000
#define N_EDGES 800000
#define IN_C 8
#define OUT_C 16
#define EDGE_F 8
#define HEADS 4
#define HID 64
#define GDIM (HEADS*HID)   // 256
#define FINAL 128
#define NEG_SLOPE 0.2f
#define EB ((N_EDGES+255)/256)      // 3125
#define NBLK 196                    // ceil(N_NODES/256)

__device__ __forceinline__ int clampn(int v) {
    return v < 0 ? 0 : (v >= N_NODES ? N_NODES - 1 : v);
}
__device__ __forceinline__ unsigned short f32_to_bf16(float f) {
    unsigned u = __float_as_uint(f);
    unsigned r = (u + 0x7fffu + ((u >> 16) & 1u)) >> 16;   // RNE
    return (unsigned short)r;
}
__device__ __forceinline__ float bf16lo(unsigned u) { return __uint_as_float(u << 16); }
__device__ __forceinline__ float bf16hi(unsigned u) { return __uint_as_float(u & 0xffff0000u); }

// ---------- CSR build ----------
__global__ __launch_bounds__(256) void k_hist(const int* __restrict__ dst,
                                              int* __restrict__ cnt,
                                              int* __restrict__ rnk)
{
    int e = blockIdx.x * 256 + threadIdx.x;
    if (e >= N_EDGES) return;
    rnk[e] = atomicAdd(&cnt[clampn(dst[e])], 1);
}

__global__ __launch_bounds__(256) void k_part(const int* __restrict__ cnt,
                                              int* __restrict__ part)
{
    int i = blockIdx.x * 256 + threadIdx.x;
    int v = (i < N_NODES) ? cnt[i] : 0;
#pragma unroll
    for (int off = 32; off; off >>= 1) v += __shfl_down(v, off);
    __shared__ int ws[4];
    if ((threadIdx.x & 63) == 0) ws[threadIdx.x >> 6] = v;
    __syncthreads();
    if (threadIdx.x == 0) part[blockIdx.x] = ws[0] + ws[1] + ws[2] + ws[3];
}

__global__ __launch_bounds__(256) void k_scan1(const int* __restrict__ part,
                                               int* __restrict__ partscan)
{
    int t = threadIdx.x;
    int v = (t < NBLK) ? part[t] : 0;
    int lane = t & 63, wid = t >> 6;
    int incl = v;
#pragma unroll
    for (int off = 1; off < 64; off <<= 1) {
        int u = __shfl_up(incl, off);
        if (lane >= off) incl += u;
    }
    __shared__ int wsum[4];
    if (lane == 63) wsum[wid] = incl;
    __syncthreads();
    int add = 0;
    for (int w = 0; w < wid; w++) add += wsum[w];
    partscan[t] = incl - v + add;   // exclusive
}

__global__ __launch_bounds__(256) void k_add(const int* __restrict__ cnt,
                                             const int* __restrict__ partscan,
                                             int* __restrict__ offs)
{
    int i = blockIdx.x * 256 + threadIdx.x;
    int v = (i < N_NODES) ? cnt[i] : 0;
    int lane = threadIdx.x & 63, wid = threadIdx.x >> 6;
    int incl = v;
#pragma unroll
    for (int off = 1; off < 64; off <<= 1) {
        int u = __shfl_up(incl, off);
        if (lane >= off) incl += u;
    }
    __shared__ int wsum[4];
    if (lane == 63) wsum[wid] = incl;
    __syncthreads();
    int add = partscan[blockIdx.x];
    for (int w = 0; w < wid; w++) add += wsum[w];
    if (i < N_NODES) offs[i] = incl - v + add;
    if (i == 0) offs[N_NODES] = N_EDGES;
}

// ---------- K_scatter: (src, edge-id) pairs into dst-CSR order ----------
__global__ __launch_bounds__(256) void k_scatter(
    const int* __restrict__ src, const int* __restrict__ dst,
    const int* __restrict__ rnk, const int* __restrict__ offs,
    int2* __restrict__ se_csr)
{
    int e = blockIdx.x * 256 + threadIdx.x;
    if (e >= N_EDGES) return;
    int p = offs[clampn(dst[e])] + rnk[e];
    se_csr[p] = make_int2(clampn(src[e]), e);
}

// ---------- K2T: T-factorized NNConv aggregate + node transform + attention logits ----------
// agg[d,o] = sum_{f,i} W[f,i,o]*T[d,f,i] + sum_i b[i,o]*xs[d,i]
// where T[d,f,i] = sum_{e->d} ea[e,f]*x[s_e,i], xs[d,i] = sum_{e->d} x[s_e,i].
// One wave per node; lane l owns (f,i)=(l>>3,l&7). Per edge: 2 broadcast loads + 1 FMA.
__global__ __launch_bounds__(256) void k2T_node(
    const float* __restrict__ x,
    const int2* __restrict__ se_csr, const int* __restrict__ offs,
    const float* __restrict__ ea,
    const float* __restrict__ mlp_w, const float* __restrict__ mlp_b,
    const float* __restrict__ ecc_root, const float* __restrict__ ecc_bias,
    const float* __restrict__ gat_lin,
    const float* __restrict__ att_src_w, const float* __restrict__ att_dst_w,
    unsigned short* __restrict__ g_bf, float* __restrict__ asrc, float* __restrict__ adst)
{
    __shared__ float smW[EDGE_F * IN_C * OUT_C];   // [j=f*8+i][o] == mlp_w layout verbatim
    __shared__ float smb[IN_C * OUT_C];
    __shared__ float sT[4][64];
    __shared__ float sxs[4][8];
    for (int i = threadIdx.x; i < EDGE_F * IN_C * OUT_C; i += 256) smW[i] = mlp_w[i];
    for (int i = threadIdx.x; i < IN_C * OUT_C; i += 256) smb[i] = mlp_b[i];

    int wid = threadIdx.x >> 6, lane = threadIdx.x & 63;
    int n = blockIdx.x * 4 + wid;
    bool alive = (n < N_NODES);

    float t0 = 0.f, t1 = 0.f, t2 = 0.f, t3 = 0.f, xs = 0.f;
    if (alive) {
        int f = lane >> 3, i = lane & 7;
        int beg = offs[n], end = offs[n + 1];
        int j = beg;
        for (; j + 3 < end; j += 4) {
            int2 se0 = se_csr[j],     se1 = se_csr[j + 1];
            int2 se2 = se_csr[j + 2], se3 = se_csr[j + 3];
            float a0 = ea[(size_t)se0.y * EDGE_F + f];
            float a1 = ea[(size_t)se1.y * EDGE_F + f];
            float a2 = ea[(size_t)se2.y * EDGE_F + f];
            float a3 = ea[(size_t)se3.y * EDGE_F + f];
            float x0 = x[se0.x * IN_C + i];
            float x1 = x[se1.x * IN_C + i];
            float x2 = x[se2.x * IN_C + i];
            float x3 = x[se3.x * IN_C + i];
            t0 += a0 * x0; t1 += a1 * x1; t2 += a2 * x2; t3 += a3 * x3;
            xs += (x0 + x1) + (x2 + x3);
        }
        for (; j < end; j++) {
            int2 se = se_csr[j];
            float a = ea[(size_t)se.y * EDGE_F + f];
            float xv = x[se.x * IN_C + i];
            t0 += a * xv;
            xs += xv;
        }
        sT[wid][lane] = (t0 + t1) + (t2 + t3);
        if (f == 0) sxs[wid][i] = xs;
    }
    __syncthreads();
    if (!alive) return;

    int o = lane & 15;
    float hv = 0.f;
    if (lane < 16) {
        float v = ecc_bias[o];
#pragma unroll 8
        for (int jj = 0; jj < 64; jj++)
            v += smW[jj * OUT_C + o] * sT[wid][jj];
#pragma unroll
        for (int ii = 0; ii < IN_C; ii++) {
            v += smb[ii * OUT_C + o] * sxs[wid][ii];
            v += x[n * IN_C + ii] * ecc_root[ii * OUT_C + o];
        }
        hv = fmaxf(v, 0.f);
    }

    float gv[4] = {0.f, 0.f, 0.f, 0.f};
#pragma unroll
    for (int k = 0; k < OUT_C; k++) {
        float hk = __shfl(hv, k);
#pragma unroll
        for (int j = 0; j < 4; j++)
            gv[j] += hk * gat_lin[k * GDIM + j * 64 + lane];
    }
#pragma unroll
    for (int j = 0; j < 4; j++)
        g_bf[(size_t)n * GDIM + j * 64 + lane] = f32_to_bf16(gv[j]);

    float vs[4], vd[4];
#pragma unroll
    for (int j = 0; j < 4; j++) {
        vs[j] = gv[j] * att_src_w[j * 64 + lane];
        vd[j] = gv[j] * att_dst_w[j * 64 + lane];
    }
#pragma unroll
    for (int off = 32; off; off >>= 1) {
#pragma unroll
        for (int j = 0; j < 4; j++) {
            vs[j] += __shfl_down(vs[j], off);
            vd[j] += __shfl_down(vd[j], off);
        }
    }
    if (lane == 0) {
#pragma unroll
        for (int j = 0; j < 4; j++) {
            asrc[n * HEADS + j] = vs[j];
            adst[n * HEADS + j] = vd[j];
        }
    }
}

// ---------- K_gat: single-loop fused softmax+aggregate, inline alpha ----------
__global__ __launch_bounds__(256) void k_gat(
    const int* __restrict__ offs, const int2* __restrict__ se_csr,
    const float* __restrict__ asrc, const float* __restrict__ adst,
    const unsigned short* __restrict__ g_bf, unsigned short* __restrict__ outg)
{
    int n = blockIdx.x, t = threadIdx.x;
    int lane32 = t & 31, grp = t >> 5;
    int hh = lane32 >> 3;
    int beg = offs[n], deg = offs[n + 1] - beg;

    float adsth = adst[n * HEADS + hh];

    float acc[8];
#pragma unroll
    for (int k = 0; k < 8; k++) acc[k] = 0.f;
    float denp = 0.f;

    for (int j = grp; j < deg; j += 8) {
        int s = se_csr[beg + j].x;
        float v = asrc[s * HEADS + hh] + adsth;
        v = v > 0.f ? v : NEG_SLOPE * v;
        float p = __expf(v);
        denp += p;
        uint4 gv = *(const uint4*)&g_bf[(size_t)s * GDIM + lane32 * 8];
        acc[0] += p * bf16lo(gv.x);
        acc[1] += p * bf16hi(gv.x);
        acc[2] += p * bf16lo(gv.y);
        acc[3] += p * bf16hi(gv.y);
        acc[4] += p * bf16lo(gv.z);
        acc[5] += p * bf16hi(gv.z);
        acc[6] += p * bf16lo(gv.w);
        acc[7] += p * bf16hi(gv.w);
    }

    __shared__ float s_acc[8][GDIM];    // 8 KB
    __shared__ float s_den[8][HEADS];
    *(float4*)&s_acc[grp][lane32 * 8]     = make_float4(acc[0], acc[1], acc[2], acc[3]);
    *(float4*)&s_acc[grp][lane32 * 8 + 4] = make_float4(acc[4], acc[5], acc[6], acc[7]);
    if ((lane32 & 7) == 0) s_den[grp][hh] = denp;
    __syncthreads();

    int head = t >> 6;
    float den = 0.f, v = 0.f;
#pragma unroll
    for (int g2 = 0; g2 < 8; g2++) {
        den += s_den[g2][head];
        v += s_acc[g2][t];
    }
    outg[(size_t)n * GDIM + t] = f32_to_bf16(v / (den + 1e-16f));
}

// ---------- K6: y = relu(outg + gat_bias) @ fc_w + fc_b ----------
#define BM 64
#define BK6 16
__global__ __launch_bounds__(256) void k6_final(
    const unsigned short* __restrict__ outg, const float* __restrict__ gat_bias,
    const float* __restrict__ fc_w, const float* __restrict__ fc_b,
    float* __restrict__ y)
{
    __shared__ float sA[BK6][BM + 4];
    __shared__ float sW[BK6][FINAL];
    int tid = threadIdx.x;
    int r0 = blockIdx.x * BM;
    int tcol = (tid & 31) * 4;
    int trow = (tid >> 5) * 8;

    float acc[8][4];
#pragma unroll
    for (int r = 0; r < 8; r++)
#pragma unroll
        for (int c = 0; c < 4; c++) acc[r][c] = 0.f;

    int ar = tid >> 2;
    int ak = (tid & 3) * 4;

    for (int k0 = 0; k0 < GDIM; k0 += BK6) {
        int row = r0 + ar;
        float4 av = make_float4(0.f, 0.f, 0.f, 0.f);
        if (row < N_NODES) {
            uint2 raw = *(const uint2*)&outg[(size_t)row * GDIM + k0 + ak];
            av = make_float4(bf16lo(raw.x), bf16hi(raw.x), bf16lo(raw.y), bf16hi(raw.y));
        }
        float4 bv = *(const float4*)&gat_bias[k0 + ak];
        av.x = fmaxf(av.x + bv.x, 0.f);
        av.y = fmaxf(av.y + bv.y, 0.f);
        av.z = fmaxf(av.z + bv.z, 0.f);
        av.w = fmaxf(av.w + bv.w, 0.f);
        sA[ak + 0][ar] = av.x;
        sA[ak + 1][ar] = av.y;
        sA[ak + 2][ar] = av.z;
        sA[ak + 3][ar] = av.w;
#pragma unroll
        for (int p = 0; p < 2; p++) {
            int kk = (tid >> 5) + p * 8;
            int c = (tid & 31) * 4;
            *(float4*)&sW[kk][c] = *(const float4*)&fc_w[(size_t)(k0 + kk) * FINAL + c];
        }
        __syncthreads();
#pragma unroll
        for (int kk = 0; kk < BK6; kk++) {
            float4 w = *(const float4*)&sW[kk][tcol];
            float4 a0 = *(const float4*)&sA[kk][trow];
            float4 a1 = *(const float4*)&sA[kk][trow + 4];
            float a[8] = {a0.x, a0.y, a0.z, a0.w, a1.x, a1.y, a1.z, a1.w};
#pragma unroll
            for (int r = 0; r < 8; r++) {
                acc[r][0] += a[r] * w.x;
                acc[r][1] += a[r] * w.y;
                acc[r][2] += a[r] * w.z;
                acc[r][3] += a[r] * w.w;
            }
        }
        __syncthreads();
    }

    float4 fb = *(const float4*)&fc_b[tcol];
#pragma unroll
    for (int r = 0; r < 8; r++) {
        int row = r0 + trow + r;
        if (row < N_NODES) {
            *(float4*)&y[(size_t)row * FINAL + tcol] =
                make_float4(acc[r][0] + fb.x, acc[r][1] + fb.y,
                            acc[r][2] + fb.z, acc[r][3] + fb.w);
        }
    }
}

extern "C" void kernel_launch(void* const* d_in, const int* in_sizes, int n_in,
                              void* d_out, int out_size, void* d_ws, size_t ws_size,
                              hipStream_t stream)
{
    const float* x        = (const float*)d_in[0];
    const int*   ei       = (const int*)d_in[1];
    const float* ea       = (const float*)d_in[2];
    const float* ecc_root = (const float*)d_in[3];
    const float* ecc_bias = (const float*)d_in[4];
    const float* mlp_w    = (const float*)d_in[5];
    const float* mlp_b    = (const float*)d_in[6];
    const float* gat_lin  = (const float*)d_in[7];
    const float* att_src  = (const float*)d_in[8];
    const float* att_dst  = (const float*)d_in[9];
    const float* gat_bias = (const float*)d_in[10];
    const float* fc_w     = (const float*)d_in[11];
    const float* fc_b     = (const float*)d_in[12];
    float* y = (float*)d_out;

    const int* src = ei;
    const int* dst = ei + N_EDGES;

    // workspace layout
    unsigned short* g_bf = (unsigned short*)d_ws;                        // N*256 bf16 (25.6 MB)
    unsigned short* outg = g_bf + (size_t)N_NODES * GDIM;                // N*256 bf16 (25.6 MB)
    float* asrc = (float*)(outg + (size_t)N_NODES * GDIM);               // N*4
    float* adst = asrc + (size_t)N_NODES * HEADS;                        // N*4
    int*   cnt      = (int*)(adst + (size_t)N_NODES * HEADS);            // N
    int*   offs     = cnt + N_NODES;                                     // N+1
    int*   part     = offs + N_NODES + 1;                                // 256
    int*   partscan = part + 256;                                        // 256
    int*   rnk      = partscan + 256;                                    // E
    int2*  se_csr   = (int2*)(rnk + N_EDGES);                            // E int2 (6.4 MB)

    hipMemsetAsync(cnt, 0, sizeof(int) * N_NODES, stream);

    k_hist   <<<EB, 256, 0, stream>>>(dst, cnt, rnk);
    k_part   <<<NBLK, 256, 0, stream>>>(cnt, part);
    k_scan1  <<<1, 256, 0, stream>>>(part, partscan);
    k_add    <<<NBLK, 256, 0, stream>>>(cnt, partscan, offs);
    k_scatter<<<EB, 256, 0, stream>>>(src, dst, rnk, offs, se_csr);

    k2T_node <<<(N_NODES + 3) / 4, 256, 0, stream>>>(x, se_csr, offs, ea,
                                                     mlp_w, mlp_b,
                                                     ecc_root, ecc_bias, gat_lin,
                                                     att_src, att_dst, g_bf, asrc, adst);
    k_gat    <<<N_NODES, 256, 0, stream>>>(offs, se_csr, asrc, adst, g_bf, outg);
    k6_final <<<(N_NODES + BM - 1) / BM, 256, 0, stream>>>(outg, gat_bias, fc_w, fc_b, y);
}